// Round 2
// baseline (269.197 us; speedup 1.0000x reference)
//
#include <hip/hip_runtime.h>

// Fused pixel_shuffle(2) + depthwise 4x4 [1,3,3,1]-outer blur, pad=2.
// Input  x: (32, 256, 64, 64) f32
// Output y: (32,  64, 129, 129) f32
//
// Separable polyphase: horizontal pass (collapses sw channel pair) -> LDS,
// vertical pass (collapses sh pair) -> global. All weights {1,3}/8 per axis.
//
// Grid partition: 4 chunks of 33 output rows (covers 0..131, clip at 128).
// Staged h rows per chunk: input rows m0-1 .. m0+17 (19 rows).

constexpr int ROWS = 33;  // output rows per chunk
constexpr int HR   = 19;  // staged h rows per chunk
constexpr int HC   = 132; // 129 cols padded to 132 (16B-aligned quads)

__global__ __launch_bounds__(256) void upsample_blur(
    const float* __restrict__ x, float* __restrict__ y)
{
    const int chunk = blockIdx.x;   // 0..3
    const int cp    = blockIdx.y;   // 0..63 output channel
    const int n     = blockIdx.z;   // 0..31 batch
    const int tid   = threadIdx.x;

    __shared__ float h[2][HR][HC];  // [sh][row][ow]  (already /8 horizontally)

    const int oh0 = chunk * ROWS;
    const int m0  = oh0 >> 1;

    const float* xb = x + ((size_t)(n * 64 + cp) * 4) * 4096; // 4 sub-channels, 64*64 each

    // ---- Phase A: horizontal polyphase filter into LDS ----
    // h[sh][rr][ow], quad t covers ow in [4t, 4t+4), t in [0,33)
    for (int idx = tid; idx < 2 * HR * 33; idx += 256) {
        const int t  = idx % 33;
        const int rr = (idx / 33) % HR;
        const int sh = idx / (33 * HR);
        const int r  = m0 - 1 + rr;     // input row (zero-pad outside [0,64))
        float h0 = 0.f, h1 = 0.f, h2 = 0.f, h3 = 0.f;
        if (r >= 0 && r < 64) {
            const float* X0 = xb + (sh * 2 + 0) * 4096 + r * 64; // sw=0 channel row
            const float* X1 = xb + (sh * 2 + 1) * 4096 + r * 64; // sw=1 channel row
            const int j = 2 * t;
            const float am1 = (j - 1 >= 0) ? X0[j - 1] : 0.f;
            const float a0  = (j     < 64) ? X0[j]     : 0.f;
            const float a1  = (j + 1 < 64) ? X0[j + 1] : 0.f;
            const float a2  = (j + 2 < 64) ? X0[j + 2] : 0.f;
            const float bm1 = (j - 1 >= 0) ? X1[j - 1] : 0.f;
            const float b0  = (j     < 64) ? X1[j]     : 0.f;
            const float b1  = (j + 1 < 64) ? X1[j + 1] : 0.f;
            // ow=4t   (even, col j):   1*a[j-1] + 3*b[j-1] + 3*a[j]   + 1*b[j]
            // ow=4t+1 (odd,  col j):   1*b[j-1] + 3*a[j]   + 3*b[j]   + 1*a[j+1]
            // ow=4t+2 (even, col j+1): 1*a[j]   + 3*b[j]   + 3*a[j+1] + 1*b[j+1]
            // ow=4t+3 (odd,  col j+1): 1*b[j]   + 3*a[j+1] + 3*b[j+1] + 1*a[j+2]
            h0 = (am1 + 3.f * a0 + 3.f * bm1 + b0) * 0.125f;
            h1 = (3.f * a0 + a1 + bm1 + 3.f * b0) * 0.125f;
            h2 = (a0 + 3.f * a1 + 3.f * b0 + b1) * 0.125f;
            h3 = (3.f * a1 + a2 + b0 + 3.f * b1) * 0.125f;
        }
        *(float4*)&h[sh][rr][4 * t] = make_float4(h0, h1, h2, h3);
    }
    __syncthreads();

    // ---- Phase B: vertical polyphase combine, write global ----
    for (int idx = tid; idx < ROWS * 33; idx += 256) {
        const int t  = idx % 33;
        const int R  = idx / 33;
        const int oh = oh0 + R;
        if (oh > 128) continue;           // only chunk 3 clips (3 rows)
        const int m   = oh >> 1;
        const int lm  = m - m0 + 1;       // staged row index of input row m
        const int par = oh & 1;

        // even oh: y = 1*h0[lm-1] + 3*h0[lm]   + 3*h1[lm-1] + 1*h1[lm]
        // odd  oh: y = 3*h0[lm]   + 1*h0[lm+1] + 1*h1[lm-1] + 3*h1[lm]
        const float4 A0 = *(const float4*)&h[0][par ? lm     : lm - 1][4 * t];
        const float4 A1 = *(const float4*)&h[0][par ? lm + 1 : lm    ][4 * t];
        const float4 B0 = *(const float4*)&h[1][lm - 1][4 * t];
        const float4 B1 = *(const float4*)&h[1][lm    ][4 * t];
        const float wA0 = par ? 3.f : 1.f;
        const float wA1 = par ? 1.f : 3.f;
        const float wB0 = par ? 1.f : 3.f;
        const float wB1 = par ? 3.f : 1.f;

        const float o0 = (wA0 * A0.x + wA1 * A1.x + wB0 * B0.x + wB1 * B1.x) * 0.125f;
        const float o1 = (wA0 * A0.y + wA1 * A1.y + wB0 * B0.y + wB1 * B1.y) * 0.125f;
        const float o2 = (wA0 * A0.z + wA1 * A1.z + wB0 * B0.z + wB1 * B1.z) * 0.125f;
        const float o3 = (wA0 * A0.w + wA1 * A1.w + wB0 * B0.w + wB1 * B1.w) * 0.125f;

        float* yp = y + ((size_t)(n * 64 + cp) * 129 + oh) * 129 + 4 * t;
        const int ow = 4 * t;
        yp[0] = o0;                       // ow <= 128 always
        if (ow + 1 < 129) yp[1] = o1;
        if (ow + 2 < 129) yp[2] = o2;
        if (ow + 3 < 129) yp[3] = o3;
    }
}

extern "C" void kernel_launch(void* const* d_in, const int* in_sizes, int n_in,
                              void* d_out, int out_size, void* d_ws, size_t ws_size,
                              hipStream_t stream) {
    const float* x = (const float*)d_in[0];
    float* yp = (float*)d_out;
    dim3 grid(4, 64, 32);   // (row-chunk, c', n)
    upsample_blur<<<grid, dim3(256), 0, stream>>>(x, yp);
}

// Round 6
// 252.706 us; speedup vs baseline: 1.0653x; 1.0653x over previous
//
#include <hip/hip_runtime.h>

// Fused pixel_shuffle(2) + depthwise 4x4 outer([1,3,3,1])/64 blur, pad=2.
// Input  x: (32, 256, 64, 64) f32   -> viewed as (2048 planes-of-4, 64, 64)
// Output y: (32,  64, 129, 129) f32 -> (2048, 129, 129)
//
// Vertical-first separable polyphase, fully register-resident:
//   v_sw(oh)[j] = vertical {1,3}/8 combine of x[sh=0/1][sw] rows  (per input col j)
//   y(oh)[ow]   = horizontal {1,3}/8 combine of v_0/v_1 cols      (via __shfl)
// Each wave: one (n,c') plane x one strip of 16 input rows, lane j = input col j.
// March m down rows with register history: cur(m), prev(m-1), prev2(m-2, sh1 only),
// prefetch next(m+1). Emits odd row 2m-1 (from prev2,prev,cur) and even row 2m
// (from prev,cur) per step. No LDS, no __syncthreads.

__global__ __launch_bounds__(256) void upsample_blur(
    const float* __restrict__ x, float* __restrict__ y)
{
    const int tid  = threadIdx.x;
    const int lane = tid & 63;
    const int s    = tid >> 6;            // strip 0..3: input rows [16s, 16s+16]
    const int b    = blockIdx.x;          // 0..2047 = n*64 + c'

    const float* __restrict__ x00 = x + (size_t)b * 16384;   // sh0 sw0
    const float* __restrict__ x01 = x00 + 4096;              // sh0 sw1
    const float* __restrict__ x10 = x00 + 8192;              // sh1 sw0
    const float* __restrict__ x11 = x00 + 12288;             // sh1 sw1
    float* __restrict__ yb = y + (size_t)b * 16641;          // 129*129

    const int m0 = s << 4;

    float q10, q11;             // x1*[m-2]
    float p00, p01, p10, p11;   // x**[m-1]
    float c00, c01, c10, c11;   // x**[m]
    float n00, n01, n10, n11;   // x**[m+1] (prefetch)

    // ---- warm-up ----
    if (s > 0) {
        const int off2 = (m0 - 2) * 64 + lane;
        const int off1 = (m0 - 1) * 64 + lane;
        q10 = x10[off2]; q11 = x11[off2];
        p00 = x00[off1]; p01 = x01[off1];
        p10 = x10[off1]; p11 = x11[off1];
    } else {
        q10 = q11 = 0.f;
        p00 = p01 = p10 = p11 = 0.f;
    }
    {
        const int off0 = m0 * 64 + lane;
        c00 = x00[off0]; c01 = x01[off0];
        c10 = x10[off0]; c11 = x11[off0];
    }

    const int mlast = m0 + 16;
    const int elast = (s == 3) ? 64 : (m0 + 15);  // last m that emits an even row

    for (int i = 0; i <= 16; ++i) {
        const int m = m0 + i;

        // prefetch row m+1 (zeros past the image / past strip end)
        if (m < mlast && m + 1 < 64) {
            const int offn = (m + 1) * 64 + lane;
            n00 = x00[offn]; n01 = x01[offn];
            n10 = x10[offn]; n11 = x11[offn];
        } else {
            n00 = n01 = n10 = n11 = 0.f;
        }

        if (m > m0) {
            // odd output row oh = 2m-1:
            // v_sw = (x1sw[m-2] + 3*x0sw[m-1] + 3*x1sw[m-1] + x0sw[m]) / 8
            const float v0 = (3.f * p00 + c00 + q10 + 3.f * p10) * 0.125f;
            const float v1 = (3.f * p01 + c01 + q11 + 3.f * p11) * 0.125f;
            float v0m = __shfl_up(v0, 1);   if (lane == 0)  v0m = 0.f;
            float v1m = __shfl_up(v1, 1);   if (lane == 0)  v1m = 0.f;
            float v0p = __shfl_down(v0, 1); if (lane == 63) v0p = 0.f;
            float* r = yb + (size_t)(2 * m - 1) * 129;
            r[2 * lane]     = (v0m + 3.f * v0 + 3.f * v1m + v1) * 0.125f;
            r[2 * lane + 1] = (3.f * v0 + v0p + v1m + 3.f * v1) * 0.125f;
            if (lane == 63) r[128] = (v0 + 3.f * v1) * 0.125f;
        }
        if (m <= elast) {
            // even output row oh = 2m:
            // v_sw = (x0sw[m-1] + 3*x0sw[m] + 3*x1sw[m-1] + x1sw[m]) / 8
            const float v0 = (p00 + 3.f * c00 + 3.f * p10 + c10) * 0.125f;
            const float v1 = (p01 + 3.f * c01 + 3.f * p11 + c11) * 0.125f;
            float v0m = __shfl_up(v0, 1);   if (lane == 0)  v0m = 0.f;
            float v1m = __shfl_up(v1, 1);   if (lane == 0)  v1m = 0.f;
            float v0p = __shfl_down(v0, 1); if (lane == 63) v0p = 0.f;
            float* r = yb + (size_t)(2 * m) * 129;
            r[2 * lane]     = (v0m + 3.f * v0 + 3.f * v1m + v1) * 0.125f;
            r[2 * lane + 1] = (3.f * v0 + v0p + v1m + 3.f * v1) * 0.125f;
            if (lane == 63) r[128] = (v0 + 3.f * v1) * 0.125f;
        }

        // rotate history
        q10 = p10; q11 = p11;
        p00 = c00; p01 = c01; p10 = c10; p11 = c11;
        c00 = n00; c01 = n01; c10 = n10; c11 = n11;
    }
}

extern "C" void kernel_launch(void* const* d_in, const int* in_sizes, int n_in,
                              void* d_out, int out_size, void* d_ws, size_t ws_size,
                              hipStream_t stream) {
    const float* x = (const float*)d_in[0];
    float* yp = (float*)d_out;
    upsample_blur<<<dim3(2048), dim3(256), 0, stream>>>(x, yp);
}

// Round 7
// 236.702 us; speedup vs baseline: 1.1373x; 1.0676x over previous
//
#include <hip/hip_runtime.h>

// Fused pixel_shuffle(2) + depthwise 4x4 outer([1,3,3,1])/64 blur, pad=2.
// Input  x: (32, 256, 64, 64) f32   -> viewed as (2048 planes-of-4, 64, 64)
// Output y: (32,  64, 129, 129) f32 -> (2048, 129, 129)
//
// Vertical-first separable polyphase. Each wave: one (n,c') plane x one strip
// of 16 input rows, lane j = input col j.
// FULL-STRIP REGISTER PRELOAD: all ~74 row-loads issued before any compute or
// store (so no s_waitcnt ever drains stores -> pure latency amortization),
// then an unrolled compute/store march over 17 input rows emitting 33 output
// rows. All array indices compile-time (full unroll) -> stays in VGPRs.

__global__ __launch_bounds__(256, 4) void upsample_blur(
    const float* __restrict__ x, float* __restrict__ y)
{
    const int tid  = threadIdx.x;
    const int lane = tid & 63;
    const int s    = tid >> 6;            // strip 0..3: input rows [16s, 16s+16]
    const int b    = blockIdx.x;          // 0..2047 = n*64 + c'

    const float* __restrict__ x00 = x + (size_t)b * 16384;   // sh0 sw0
    const float* __restrict__ x01 = x00 + 4096;              // sh0 sw1
    const float* __restrict__ x10 = x00 + 8192;              // sh1 sw0
    const float* __restrict__ x11 = x00 + 12288;             // sh1 sw1
    float* __restrict__ yb = y + (size_t)b * 16641;          // 129*129

    const int m0 = s << 4;

    // sh0 rows m0-1 .. m0+16  (18), sh1 rows m0-2 .. m0+16 (19), per sw.
    float a0[18], a1[18], b0v[19], b1v[19];

    #pragma unroll
    for (int k = 0; k < 18; ++k) {
        const int r  = m0 - 1 + k;
        const int rc = (r < 0) ? 0 : (r > 63 ? 63 : r);   // clamp: load always in-bounds
        const bool v = (r >= 0) && (r < 64);              // wave-uniform
        const float t0 = x00[rc * 64 + lane];
        const float t1 = x01[rc * 64 + lane];
        a0[k] = v ? t0 : 0.f;
        a1[k] = v ? t1 : 0.f;
    }
    #pragma unroll
    for (int k = 0; k < 19; ++k) {
        const int r  = m0 - 2 + k;
        const int rc = (r < 0) ? 0 : (r > 63 ? 63 : r);
        const bool v = (r >= 0) && (r < 64);
        const float t0 = x10[rc * 64 + lane];
        const float t1 = x11[rc * 64 + lane];
        b0v[k] = v ? t0 : 0.f;
        b1v[k] = v ? t1 : 0.f;
    }

    // ---- compute + store march (no loads beyond this point) ----
    #pragma unroll
    for (int i = 0; i <= 16; ++i) {
        const int m = m0 + i;
        const float p00 = a0[i],  c00 = a0[i + 1];   // sh0 sw0: rows m-1, m
        const float p01 = a1[i],  c01 = a1[i + 1];   // sh0 sw1
        const float q10 = b0v[i], p10 = b0v[i + 1], c10 = b0v[i + 2]; // sh1 sw0: m-2,m-1,m
        const float q11 = b1v[i], p11 = b1v[i + 1], c11 = b1v[i + 2]; // sh1 sw1

        if (i > 0) {
            // odd output row oh = 2m-1:
            // v_sw = (x1sw[m-2] + 3*x0sw[m-1] + 3*x1sw[m-1] + x0sw[m]) / 8
            const float v0 = (3.f * p00 + c00 + q10 + 3.f * p10) * 0.125f;
            const float v1 = (3.f * p01 + c01 + q11 + 3.f * p11) * 0.125f;
            float v0m = __shfl_up(v0, 1);   if (lane == 0)  v0m = 0.f;
            float v1m = __shfl_up(v1, 1);   if (lane == 0)  v1m = 0.f;
            float v0p = __shfl_down(v0, 1); if (lane == 63) v0p = 0.f;
            float* r = yb + (size_t)(2 * m - 1) * 129;
            r[2 * lane]     = (v0m + 3.f * v0 + 3.f * v1m + v1) * 0.125f;
            r[2 * lane + 1] = (3.f * v0 + v0p + v1m + 3.f * v1) * 0.125f;
            if (lane == 63) r[128] = (v0 + 3.f * v1) * 0.125f;
        }
        if (i < 16 || s == 3) {
            // even output row oh = 2m:
            // v_sw = (x0sw[m-1] + 3*x0sw[m] + 3*x1sw[m-1] + x1sw[m]) / 8
            const float v0 = (p00 + 3.f * c00 + 3.f * p10 + c10) * 0.125f;
            const float v1 = (p01 + 3.f * c01 + 3.f * p11 + c11) * 0.125f;
            float v0m = __shfl_up(v0, 1);   if (lane == 0)  v0m = 0.f;
            float v1m = __shfl_up(v1, 1);   if (lane == 0)  v1m = 0.f;
            float v0p = __shfl_down(v0, 1); if (lane == 63) v0p = 0.f;
            float* r = yb + (size_t)(2 * m) * 129;
            r[2 * lane]     = (v0m + 3.f * v0 + 3.f * v1m + v1) * 0.125f;
            r[2 * lane + 1] = (3.f * v0 + v0p + v1m + 3.f * v1) * 0.125f;
            if (lane == 63) r[128] = (v0 + 3.f * v1) * 0.125f;
        }
    }
}

extern "C" void kernel_launch(void* const* d_in, const int* in_sizes, int n_in,
                              void* d_out, int out_size, void* d_ws, size_t ws_size,
                              hipStream_t stream) {
    const float* x = (const float*)d_in[0];
    float* yp = (float*)d_out;
    upsample_blur<<<dim3(2048), dim3(256), 0, stream>>>(x, yp);
}